// Round 5
// baseline (67.387 us; speedup 1.0000x reference)
//
#include <hip/hip_runtime.h>

// Problem constants (fixed by reference setup_inputs)
#define BN 512
#define CCH 32
#define TT 4096

// One thread per output bin. Window per bin is <= ceil(4095/256)+1 = 17
// floats -> spans at most 5 float4 blocks. Load all 5 (clamped), mask in
// the accumulation. f and m share the same window -> 10 loads/thread.
__global__ __launch_bounds__(256) void pool_direct(
    const float* __restrict__ f, const float* __restrict__ m,
    const int* __restrict__ vlen,
    float* __restrict__ out_f, float* __restrict__ out_m,
    int K, int kshift, int total)
{
    int tid = blockIdx.x * 256 + threadIdx.x;
    if (tid >= total) return;

    int k, bc;
    if (kshift >= 0) { k = tid & (K - 1); bc = tid >> kshift; }
    else             { k = tid % K;       bc = tid / K; }
    int b = bc / CCH;

    // valid_lengths may be int64 (JAX x64 on) or int32 (x64 off).
    // int64 LE: all high words are 0 since values < 4096.
    bool is64 = ((vlen[1] | vlen[3] | vlen[5] | vlen[7] |
                  vlen[9] | vlen[11] | vlen[13] | vlen[15]) == 0);
    int len = is64 ? vlen[2 * b] : vlen[b];
    int L   = len < 1 ? 1 : (len > TT ? TT : len);
    int off = TT - L;

    unsigned uL = (unsigned)L, uK = (unsigned)K;
    unsigned p0 = uL * (unsigned)k;
    unsigned p1 = uL * (unsigned)(k + 1) + uK - 1u;
    int si, ei;
    if (kshift >= 0) { si = off + (int)(p0 >> kshift); ei = off + (int)(p1 >> kshift); }
    else             { si = off + (int)(p0 / uK);      ei = off + (int)(p1 / uK); }
    if (ei > TT) ei = TT;
    int count = ei - si;
    if (count < 1) { count = 1; ei = si + 1; }

    const float* fr = f + (size_t)bc * TT;
    const float* mr = m + (size_t)bc * TT;

    int sblk = si >> 2;
    int eblk = (ei - 1) >> 2;
    int nb   = eblk - sblk;            // 0..4 extra blocks beyond the first

    // Clamped block indices (duplicates get masked out in ACC).
    int i0 = sblk;
    int i1 = sblk + (nb < 1 ? nb : 1);
    int i2 = sblk + (nb < 2 ? nb : 2);
    int i3 = sblk + (nb < 3 ? nb : 3);
    int i4 = sblk + (nb < 4 ? nb : 4);

    // Issue all 10 loads back-to-back (independent -> all in flight).
    float4 F0 = *(const float4*)(fr + (i0 << 2));
    float4 F1 = *(const float4*)(fr + (i1 << 2));
    float4 F2 = *(const float4*)(fr + (i2 << 2));
    float4 F3 = *(const float4*)(fr + (i3 << 2));
    float4 F4 = *(const float4*)(fr + (i4 << 2));
    float4 M0 = *(const float4*)(mr + (i0 << 2));
    float4 M1 = *(const float4*)(mr + (i1 << 2));
    float4 M2 = *(const float4*)(mr + (i2 << 2));
    float4 M3 = *(const float4*)(mr + (i3 << 2));
    float4 M4 = *(const float4*)(mr + (i4 << 2));

    float af = 0.0f, am = 0.0f;
#define ACC(I, BI, F, M)                                                   \
    do {                                                                   \
        int tb = (BI) << 2;                                                \
        bool oki = ((I) <= nb);                                            \
        { int t = tb;     float w = (oki && t >= si && t < ei) ? 1.f : 0.f;\
          af = fmaf(w, F.x, af); am = fmaf(w, M.x, am); }                  \
        { int t = tb + 1; float w = (oki && t >= si && t < ei) ? 1.f : 0.f;\
          af = fmaf(w, F.y, af); am = fmaf(w, M.y, am); }                  \
        { int t = tb + 2; float w = (oki && t >= si && t < ei) ? 1.f : 0.f;\
          af = fmaf(w, F.z, af); am = fmaf(w, M.z, am); }                  \
        { int t = tb + 3; float w = (oki && t >= si && t < ei) ? 1.f : 0.f;\
          af = fmaf(w, F.w, af); am = fmaf(w, M.w, am); }                  \
    } while (0)

    ACC(0, i0, F0, M0);
    ACC(1, i1, F1, M1);
    ACC(2, i2, F2, M2);
    ACC(3, i3, F3, M3);
    ACC(4, i4, F4, M4);
#undef ACC

    float inv = 1.0f / (float)count;
    // tid == bc*K + k by construction -> coalesced output writes.
    out_f[tid] = af * inv;
    out_m[tid] = am * inv;
}

extern "C" void kernel_launch(void* const* d_in, const int* in_sizes, int n_in,
                              void* d_out, int out_size, void* d_ws, size_t ws_size,
                              hipStream_t stream) {
    const float* f    = (const float*)d_in[0];
    const float* m    = (const float*)d_in[1];
    const int*   vlen = (const int*)d_in[2];

    // K derived from output size: out = 2 * BN * C * K floats
    int K = out_size / (2 * BN * CCH);
    if (K < 1) K = 1;
    int kshift = ((K & (K - 1)) == 0) ? __builtin_ctz(K) : -1;

    float* out_f = (float*)d_out;
    float* out_m = out_f + (size_t)BN * CCH * K;

    int total = BN * CCH * K;
    int grid  = (total + 255) / 256;
    pool_direct<<<grid, 256, 0, stream>>>(f, m, vlen, out_f, out_m, K, kshift, total);
}

// Round 7
// 59.572 us; speedup vs baseline: 1.1312x; 1.1312x over previous
//
#include <hip/hip_runtime.h>

// Problem constants (fixed by reference setup_inputs)
#define BN 512
#define CCH 32
#define TT 4096
#define RPB 16   // rows per block; grid = BN*CCH/RPB = 1024 = 4 blocks/CU

// Pad LDS by +4 floats per 32: float4 (16B) staging writes stay 16B-aligned
// (4-aligned idx -> 4-aligned padded idx); per-lane b128 bin reads get their
// start banks spread 0,16,4,20,8,24,12,28 across lanes -> ~conflict-free.
// NOTE: writes and reads must BOTH use ABSOLUTE element indices (R6 bug:
// reads used window-relative indices -> wrong LDS cells for short rows).
__device__ __forceinline__ int padidx(int i) { return i + ((i >> 5) << 2); }
// padidx of the first element of float4-block b: padidx(4b) = 4b + ((b>>3)<<2)
__device__ __forceinline__ int padblk(int b) { return (b << 2) + ((b >> 3) << 2); }

__global__ __launch_bounds__(256, 4) void pool_pipe2(
    const float* __restrict__ f, const float* __restrict__ m,
    const int* __restrict__ vlen,
    float* __restrict__ out_f, float* __restrict__ out_m, int K)
{
    __shared__ float sf[4608];   // padidx(4095) = 4603 < 4608
    __shared__ float sm[4608];

    const int tid = threadIdx.x;
    const int nb_grid = gridDim.x;

    // valid_lengths may be int64 (JAX x64 on) or int32 (x64 off).
    // int64 LE: all high words are 0 since values < 4096.
    bool is64 = ((vlen[1] | vlen[3] | vlen[5] | vlen[7] |
                  vlen[9] | vlen[11] | vlen[13] | vlen[15]) == 0);

    // Named float4 prefetch registers (static indices -> stay in VGPRs).
    float4 rf0, rf1, rf2, rf3, rm0, rm1, rm2, rm3;
    int bc, L, off, a0, nv;

    #define ROW_PARAMS(j)                                              \
        do {                                                           \
            bc = blockIdx.x + (j) * nb_grid;                           \
            int b_ = bc / CCH;                                         \
            int len_ = is64 ? vlen[2 * b_] : vlen[b_];                 \
            L = len_ < 1 ? 1 : (len_ > TT ? TT : len_);                \
            off = TT - L;                                              \
            a0 = off & ~3;                                             \
            nv = (TT - a0) >> 2;                                       \
        } while (0)

    #define ISSUE_LOADS()                                              \
        do {                                                           \
            const float* fr_ = f + (size_t)bc * TT + a0;               \
            const float* mr_ = m + (size_t)bc * TT + a0;               \
            int i0_ = tid, i1_ = tid + 256, i2_ = tid + 512, i3_ = tid + 768; \
            if (i0_ < nv) { rf0 = *(const float4*)(fr_ + 4 * i0_);     \
                            rm0 = *(const float4*)(mr_ + 4 * i0_); }   \
            if (i1_ < nv) { rf1 = *(const float4*)(fr_ + 4 * i1_);     \
                            rm1 = *(const float4*)(mr_ + 4 * i1_); }   \
            if (i2_ < nv) { rf2 = *(const float4*)(fr_ + 4 * i2_);     \
                            rm2 = *(const float4*)(mr_ + 4 * i2_); }   \
            if (i3_ < nv) { rf3 = *(const float4*)(fr_ + 4 * i3_);     \
                            rm3 = *(const float4*)(mr_ + 4 * i3_); }   \
        } while (0)

    // Prologue: prefetch row 0.
    ROW_PARAMS(0);
    ISSUE_LOADS();

    for (int j = 0; j < RPB; ++j) {
        // Write the prefetched row into LDS (absolute padded indices).
        {
            int i0_ = tid, i1_ = tid + 256, i2_ = tid + 512, i3_ = tid + 768;
            if (i0_ < nv) { int p = padidx(a0 + 4 * i0_);
                            *(float4*)&sf[p] = rf0; *(float4*)&sm[p] = rm0; }
            if (i1_ < nv) { int p = padidx(a0 + 4 * i1_);
                            *(float4*)&sf[p] = rf1; *(float4*)&sm[p] = rm1; }
            if (i2_ < nv) { int p = padidx(a0 + 4 * i2_);
                            *(float4*)&sf[p] = rf2; *(float4*)&sm[p] = rm2; }
            if (i3_ < nv) { int p = padidx(a0 + 4 * i3_);
                            *(float4*)&sf[p] = rf3; *(float4*)&sm[p] = rm3; }
        }
        __syncthreads();

        int cbc = bc, cL = L, coff = off;

        // Issue next row's global loads NOW — they fly during bin-compute.
        if (j + 1 < RPB) {
            ROW_PARAMS(j + 1);
            ISSUE_LOADS();
        }

        // Bin-compute: one bin per thread, 5 clamped b128 reads per array,
        // ABSOLUTE indices throughout.
        for (int k = tid; k < K; k += 256) {
            unsigned uL = (unsigned)cL, uK = (unsigned)K, uk = (unsigned)k;
            int si = coff + (int)((uL * uk) / uK);
            int ei = coff + (int)((uL * (uk + 1u) + uK - 1u) / uK);
            if (ei > TT) ei = TT;
            int count = ei - si;
            if (count < 1) count = 1;

            int re = ei - 1;             // absolute last element
            int b0 = si >> 2;            // absolute first block
            int nbw = (re >> 2) - b0;    // 0..4 extra blocks

            float af = 0.0f, am = 0.0f;
#define ACCB(J)                                                            \
    do {                                                                   \
        int bj = b0 + ((nbw < (J)) ? nbw : (J));                           \
        int p  = padblk(bj);                                               \
        float4 F = *(const float4*)&sf[p];                                 \
        float4 M = *(const float4*)&sm[p];                                 \
        bool oki = ((J) <= nbw);                                           \
        int u = bj << 2;                                                   \
        { float w = (oki && u     >= si && u     <= re) ? 1.f : 0.f;       \
          af = fmaf(w, F.x, af); am = fmaf(w, M.x, am); }                  \
        { float w = (oki && u + 1 >= si && u + 1 <= re) ? 1.f : 0.f;       \
          af = fmaf(w, F.y, af); am = fmaf(w, M.y, am); }                  \
        { float w = (oki && u + 2 >= si && u + 2 <= re) ? 1.f : 0.f;       \
          af = fmaf(w, F.z, af); am = fmaf(w, M.z, am); }                  \
        { float w = (oki && u + 3 >= si && u + 3 <= re) ? 1.f : 0.f;       \
          af = fmaf(w, F.w, af); am = fmaf(w, M.w, am); }                  \
    } while (0)
            ACCB(0); ACCB(1); ACCB(2); ACCB(3); ACCB(4);
#undef ACCB

            float inv = 1.0f / (float)count;
            size_t o = (size_t)cbc * K + k;
            out_f[o] = af * inv;
            out_m[o] = am * inv;
        }
        __syncthreads();
    }
    #undef ROW_PARAMS
    #undef ISSUE_LOADS
}

extern "C" void kernel_launch(void* const* d_in, const int* in_sizes, int n_in,
                              void* d_out, int out_size, void* d_ws, size_t ws_size,
                              hipStream_t stream) {
    const float* f    = (const float*)d_in[0];
    const float* m    = (const float*)d_in[1];
    const int*   vlen = (const int*)d_in[2];

    // K derived from output size: out = 2 * BN * C * K floats
    int K = out_size / (2 * BN * CCH);
    if (K < 1) K = 1;

    float* out_f = (float*)d_out;
    float* out_m = out_f + (size_t)BN * CCH * K;

    int grid = (BN * CCH) / RPB;   // 1024
    pool_pipe2<<<grid, 256, 0, stream>>>(f, m, vlen, out_f, out_m, K);
}